// Round 4
// baseline (190.645 us; speedup 1.0000x reference)
//
#include <hip/hip_runtime.h>
#include <hip/hip_bf16.h>
#include <hip/hip_fp16.h>

#define FEAT 2048
#define NCLS 751
#define NPAD 768
#define NPRB 64
#define NGAL 256
#define WSCALE 256.0f

typedef _Float16 f16x8 __attribute__((ext_vector_type(8)));
typedef float f32x4 __attribute__((ext_vector_type(4)));

__device__ __forceinline__ unsigned short f2h_u(float x) {
  union { _Float16 h; unsigned short u; } v;
  v.h = (_Float16)x;
  return v.u;
}

// ---------------------------------------------------------------------------
// Kernel 1: per-feature moments of probe/gallery -> BN scale s[f], shift t[f]
// mean[f] = E_pg[(p-g)^2] = M2p - 2 M1p M1g + M2g   (exact, cross-product)
// E[d^2]  = M4p - 4 M3p M1g + 6 M2p M2g - 4 M1p M3g + M4g
// ---------------------------------------------------------------------------
__global__ void stats_kernel(const float* __restrict__ P, const float* __restrict__ G,
                             const float* __restrict__ gamma, const float* __restrict__ beta,
                             float* __restrict__ st) {
  int fx = threadIdx.x & 31, ry = threadIdx.x >> 5;
  int f = blockIdx.x * 32 + fx;
  float a1 = 0, a2 = 0, a3 = 0, a4 = 0;
  for (int r = ry; r < NPRB; r += 8) {
    float x = P[r * FEAT + f], x2 = x * x;
    a1 += x; a2 += x2; a3 += x2 * x; a4 += x2 * x2;
  }
  float b1 = 0, b2 = 0, b3 = 0, b4 = 0;
  for (int r = ry; r < NGAL; r += 8) {
    float x = G[r * FEAT + f], x2 = x * x;
    b1 += x; b2 += x2; b3 += x2 * x; b4 += x2 * x2;
  }
  __shared__ float red[8][8][32];
  float vals[8] = {a1, a2, a3, a4, b1, b2, b3, b4};
#pragma unroll
  for (int m = 0; m < 8; ++m) red[m][ry][fx] = vals[m];
  __syncthreads();
  if (ry == 0) {
    float mm[8];
#pragma unroll
    for (int m = 0; m < 8; ++m) {
      float sum = 0.f;
#pragma unroll
      for (int r = 0; r < 8; ++r) sum += red[m][r][fx];
      mm[m] = sum;
    }
    float M1p = mm[0] * (1.f / NPRB), M2p = mm[1] * (1.f / NPRB);
    float M3p = mm[2] * (1.f / NPRB), M4p = mm[3] * (1.f / NPRB);
    float M1g = mm[4] * (1.f / NGAL), M2g = mm[5] * (1.f / NGAL);
    float M3g = mm[6] * (1.f / NGAL), M4g = mm[7] * (1.f / NGAL);
    float mean = M2p - 2.f * M1p * M1g + M2g;
    float Ed2 = M4p - 4.f * M3p * M1g + 6.f * M2p * M2g - 4.f * M1p * M3g + M4g;
    float var = Ed2 - mean * mean;
    float sv = gamma[f] / sqrtf(var + 1e-5f);
    st[f] = sv;
    st[FEAT + f] = beta[f] - mean * sv;  // t[f]
  }
}

// ---------------------------------------------------------------------------
// Kernel 2: W -> MFMA-fragment-ordered Wf + folded bias bp.
// Wf layout: [nblk=cls/16][kc=f/8][row=cls%16][8 f16], value W*s*WSCALE.
// A wave's bf fragment (16 cols x 8 feats) is then a contiguous 1 KB chunk:
// lane l reads elems nblk*32768 + kc0*128 + l*8  (global_load_dwordx4).
// One block per 16-class group; writes coalesced (thread t -> t*16 B).
// ---------------------------------------------------------------------------
__global__ void prepw_kernel(const float* __restrict__ W, const float* __restrict__ b,
                             const float* __restrict__ st,
                             unsigned short* __restrict__ Wf, float* __restrict__ bp) {
  const int nblk = blockIdx.x;       // 0..47
  const int t = threadIdx.x;
  const int row = t & 15;            // class within group
  const int c = nblk * 16 + row;
  const int kcb = t >> 4;            // 0..15
  unsigned short* wbase = Wf + (size_t)nblk * 32768;
  float part = 0.f;
#pragma unroll 4
  for (int i = 0; i < 16; ++i) {
    int kc = i * 16 + kcb;
    int f = kc * 8;
    float4 w0 = make_float4(0.f, 0.f, 0.f, 0.f), w1 = w0;
    if (c < NCLS) {
      const float4* ws = (const float4*)(W + (size_t)c * FEAT + f);
      w0 = ws[0]; w1 = ws[1];
    }
    const float4* s4 = (const float4*)(st + f);
    float4 s0 = s4[0], s1 = s4[1];
    const float4* t4 = (const float4*)(st + FEAT + f);
    float4 t0 = t4[0], t1 = t4[1];
    uint4 u;
    u.x = (unsigned int)f2h_u(w0.x * s0.x * WSCALE) | ((unsigned int)f2h_u(w0.y * s0.y * WSCALE) << 16);
    u.y = (unsigned int)f2h_u(w0.z * s0.z * WSCALE) | ((unsigned int)f2h_u(w0.w * s0.w * WSCALE) << 16);
    u.z = (unsigned int)f2h_u(w1.x * s1.x * WSCALE) | ((unsigned int)f2h_u(w1.y * s1.y * WSCALE) << 16);
    u.w = (unsigned int)f2h_u(w1.z * s1.z * WSCALE) | ((unsigned int)f2h_u(w1.w * s1.w * WSCALE) << 16);
    *(uint4*)(wbase + (size_t)kc * 128 + row * 8) = u;
    part += t0.x * w0.x + t0.y * w0.y + t0.z * w0.z + t0.w * w0.w +
            t1.x * w1.x + t1.y * w1.y + t1.z * w1.z + t1.w * w1.w;
  }
  __shared__ float red[16][16];  // [kcb][row]
  red[kcb][row] = part;
  __syncthreads();
  if (t < 16) {
    float sum = (nblk * 16 + t < NCLS) ? b[nblk * 16 + t] : 0.f;
#pragma unroll
    for (int j = 0; j < 16; ++j) sum += red[j][t];
    bp[nblk * 16 + t] = sum;
  }
}

// ---------------------------------------------------------------------------
// Kernel 3: materialize A[n,f] = (P[p,f]-G[g,f])^2 as f16, n = p*256+g.
// ---------------------------------------------------------------------------
__global__ void agen_kernel(const float* __restrict__ P, const float* __restrict__ G,
                            unsigned short* __restrict__ A) {
  int n = blockIdx.x;
  int p = n >> 8, g = n & 255;
  int f = threadIdx.x * 8;
  const float4* p4 = (const float4*)(P + (size_t)p * FEAT + f);
  const float4* g4 = (const float4*)(G + (size_t)g * FEAT + f);
  float4 pa = p4[0], pb = p4[1];
  float4 ga = g4[0], gb = g4[1];
  float d0 = pa.x - ga.x, d1 = pa.y - ga.y, d2 = pa.z - ga.z, d3 = pa.w - ga.w;
  float d4 = pb.x - gb.x, d5 = pb.y - gb.y, d6 = pb.z - gb.z, d7 = pb.w - gb.w;
  uint4 u;
  u.x = (unsigned int)f2h_u(d0 * d0) | ((unsigned int)f2h_u(d1 * d1) << 16);
  u.y = (unsigned int)f2h_u(d2 * d2) | ((unsigned int)f2h_u(d3 * d3) << 16);
  u.z = (unsigned int)f2h_u(d4 * d4) | ((unsigned int)f2h_u(d5 * d5) << 16);
  u.w = (unsigned int)f2h_u(d6 * d6) | ((unsigned int)f2h_u(d7 * d7) << 16);
  *(uint4*)(A + (size_t)n * FEAT + f) = u;
}

// ---------------------------------------------------------------------------
// Kernel 4: f16 GEMM, M=16384, N=768, K=2048. A via swizzled LDS (barriers),
// B via direct fragment loads from Wf (register ping-pong, no LDS, no copies).
// K-loop manually unrolled 2x (BK=64 per half) to alternate bf banks.
// ---------------------------------------------------------------------------
__global__ __launch_bounds__(256, 3)
void gemm_mat_kernel(const unsigned short* __restrict__ A,
                     const unsigned short* __restrict__ Wf,
                     const float* __restrict__ bp, float* __restrict__ out) {
  __shared__ unsigned short As[128 * 64];  // 16 KB, xor-swizzled slots

  const int tid = threadIdx.x;
  const int lane = tid & 63, wave = tid >> 6;
  const int mtile = blockIdx.x, ntile = blockIdx.y;

  // A staging: thread t -> row t>>3, source k-chunk (t&7)^(row&7) -> slot t&7
  const int srow = tid >> 3;
  const int sch = (tid & 7) ^ (srow & 7);
  const unsigned short* ag = A + (size_t)(mtile * 128 + srow) * FEAT + sch * 8;
  char* alds = (char*)As + wave * 1024;  // wave-uniform; HW adds lane*16

  f32x4 acc[4][4];
#pragma unroll
  for (int mi = 0; mi < 4; ++mi)
#pragma unroll
    for (int ni = 0; ni < 4; ++ni) acc[mi][ni] = (f32x4){0.f, 0.f, 0.f, 0.f};

  const int wm = (wave & 1) * 64, wn = (wave >> 1) * 64;
  const int frow = lane & 15, fsw = lane & 7, fk = lane >> 4;

  // B fragment base: nblk = ntile*8 + wn/16 + ni; lane-linear within a chunk.
  const unsigned short* wfbase =
      Wf + ((size_t)ntile * 8 + (wn >> 4)) * 32768 + lane * 8;

  // bf[kk][ni] at k-offset k0: wfbase + ni*32768 + k0*16 + kk*512
  f16x8 bfa[2][4], bfb[2][4];
#pragma unroll
  for (int kk = 0; kk < 2; ++kk)
#pragma unroll
    for (int ni = 0; ni < 4; ++ni)
      bfa[kk][ni] = *(const f16x8*)(wfbase + (size_t)ni * 32768 + kk * 512);

#define STAGE_A(K0)                                                              \
  do {                                                                           \
    __syncthreads();                                                             \
    _Pragma("unroll") for (int j = 0; j < 4; ++j)                                \
        __builtin_amdgcn_global_load_lds(                                        \
            (const __attribute__((address_space(1))) void*)(ag + (K0) +          \
                                                            (size_t)j * 32 * FEAT), \
            (__attribute__((address_space(3))) void*)(alds + j * 4096), 16, 0, 0);
#define PREFETCH_B(DST, K0)                                                      \
    _Pragma("unroll") for (int kk = 0; kk < 2; ++kk)                             \
      _Pragma("unroll") for (int ni = 0; ni < 4; ++ni)                           \
        DST[kk][ni] = *(const f16x8*)(wfbase + (size_t)ni * 32768 + (K0)*16 + kk * 512);
#define COMPUTE(SRC)                                                             \
    __syncthreads();                                                             \
    _Pragma("unroll") for (int kk = 0; kk < 2; ++kk) {                           \
      const int slot = (kk * 4 + fk) ^ fsw;                                      \
      f16x8 af[4];                                                               \
      _Pragma("unroll") for (int mi = 0; mi < 4; ++mi)                           \
          af[mi] = *(const f16x8*)(As + (wm + mi * 16 + frow) * 64 + slot * 8);  \
      _Pragma("unroll") for (int mi = 0; mi < 4; ++mi)                           \
        _Pragma("unroll") for (int ni = 0; ni < 4; ++ni)                         \
            acc[mi][ni] = __builtin_amdgcn_mfma_f32_16x16x32_f16(                \
                af[mi], SRC[kk][ni], acc[mi][ni], 0, 0, 0);                      \
    }                                                                            \
  } while (0)

  for (int k0 = 0; k0 < FEAT; k0 += 128) {
    STAGE_A(k0)
    PREFETCH_B(bfb, k0 + 64)
    COMPUTE(bfa);
    STAGE_A(k0 + 64)
    if (k0 + 128 < FEAT) { PREFETCH_B(bfa, k0 + 128) }
    COMPUTE(bfb);
  }
#undef STAGE_A
#undef PREFETCH_B
#undef COMPUTE

  // epilogue: C/D layout col=lane&15, row=(lane>>4)*4+reg; undo WSCALE, add b'
  const int col0 = ntile * 128 + wn + (lane & 15);
  const int row0 = mtile * 128 + wm + ((lane >> 4) << 2);
#pragma unroll
  for (int ni = 0; ni < 4; ++ni) {
    int col = col0 + ni * 16;
    if (col >= NCLS) continue;
    float bv = bp[col];
#pragma unroll
    for (int mi = 0; mi < 4; ++mi) {
      int row = row0 + mi * 16;
#pragma unroll
      for (int r = 0; r < 4; ++r)
        out[(size_t)(row + r) * NCLS + col] = acc[mi][ni][r] * (1.0f / WSCALE) + bv;
    }
  }
}

// ---------------------------------------------------------------------------
extern "C" void kernel_launch(void* const* d_in, const int* in_sizes, int n_in,
                              void* d_out, int out_size, void* d_ws, size_t ws_size,
                              hipStream_t stream) {
  const float* P = (const float*)d_in[0];
  const float* G = (const float*)d_in[1];
  const float* gamma = (const float*)d_in[2];
  const float* beta = (const float*)d_in[3];
  const float* W = (const float*)d_in[4];
  const float* b = (const float*)d_in[5];
  float* out = (float*)d_out;

  float* st = (float*)d_ws;                           // s[2048], t[2048]
  float* bp = st + 2 * FEAT;                          // b'[768]
  unsigned short* Wf = (unsigned short*)(bp + NPAD);  // f16 Wf [48*32768]
  unsigned short* A = Wf + (size_t)48 * 32768;        // f16 A [16384, 2048]

  hipLaunchKernelGGL(agen_kernel, dim3(NPRB * NGAL), dim3(256), 0, stream, P, G, A);
  hipLaunchKernelGGL(stats_kernel, dim3(64), dim3(256), 0, stream, P, G, gamma, beta, st);
  hipLaunchKernelGGL(prepw_kernel, dim3(48), dim3(256), 0, stream, W, b, st, Wf, bp);
  hipLaunchKernelGGL(gemm_mat_kernel, dim3(128, 6), dim3(256), 0, stream, A, Wf, bp, out);
}